// Round 10
// baseline (788.737 us; speedup 1.0000x reference)
//
#include <hip/hip_runtime.h>

typedef _Float16 f16;
typedef _Float16 f16x8 __attribute__((ext_vector_type(8)));
typedef _Float16 f16x4 __attribute__((ext_vector_type(4)));
typedef _Float16 h2 __attribute__((ext_vector_type(2)));
typedef float f32x4 __attribute__((ext_vector_type(4)));
typedef unsigned short u16;
typedef unsigned int u32;

#define DEVI __device__ __forceinline__

DEVI u16 f2h(float f) { f16 h = (f16)f; return __builtin_bit_cast(u16, h); }
DEVI float h2f(u16 u) { f16 h = __builtin_bit_cast(f16, u); return (float)h; }

// S-agnostic conflict-free LDS slot map: pair P holds 8 uint4 (2 pixels r=0,1 x 4 chunks c).
DEVI int slotf(int P, int c, int r) { return ((c + P) & 3) | (((r + (P >> 2)) & 1) << 2); }

// ============================ merged weight prep (one dispatch; saves 6 launch gaps) ============================
// bid ranges: [0,800) wconv ew2 | [800,4000) wconv ew3 | [4000,5024) wdec dw1 |
// [5024,5280) wdec dw2 | [5280,7328) cb | [7328,7332) cbn | 7332 diff-zero
__launch_bounds__(256)
__global__ void prep_all_k(const float* __restrict__ ew2, const float* __restrict__ ew3,
                           const float* __restrict__ dw1, const float* __restrict__ dw2,
                           const float* __restrict__ cb,
                           u16* __restrict__ wBf2, u16* __restrict__ wBf3,
                           u16* __restrict__ wd1f, u16* __restrict__ wd2f,
                           u16* __restrict__ cbf, float* __restrict__ cbn,
                           float* __restrict__ diff) {
    int bid = blockIdx.x, t = threadIdx.x;
    if (bid < 4000) {
        // prep_wconv: split-fp16 conv weights
        const float* src; u16* dst; int nf_sh, i;
        if (bid < 800) { src = ew2; dst = wBf2; nf_sh = 2; i = bid * 256 + t; }
        else           { src = ew3; dst = wBf3; nf_sh = 4; i = (bid - 800) * 256 + t; }
        int j = i & 7, lane = (i >> 3) & 63;
        int q = i >> 9;
        int f = q & ((1 << nf_sh) - 1); q >>= nf_sh;
        int pl = q & 1; q >>= 1;
        int icc = q & 1; int tap = q >> 1;
        int oc = (f << 4) + (lane & 15);
        int ic = icc * 32 + ((lane >> 4) << 3) + j;
        float w = src[(oc * 64 + ic) * 25 + tap];
        if (pl == 0) dst[i] = f2h(w);
        else         dst[i] = f2h((w - h2f(f2h(w))) * 4096.f);
    } else if (bid < 5280) {
        // prep_wdec: deconv weights
        const float* src; u16* dst; int icc_sh, i;
        if (bid < 5024) { src = dw1; dst = wd1f; icc_sh = 3; i = (bid - 4000) * 256 + t; }
        else            { src = dw2; dst = wd2f; icc_sh = 1; i = (bid - 5024) * 256 + t; }
        int j = i & 7, lane = (i >> 3) & 63;
        int f = (i >> 9) & 3;
        int q = i >> 11;
        int icc = q & ((1 << icc_sh) - 1); int tap = q >> icc_sh;
        int oc = (f << 4) + (lane & 15);
        int ic = icc * 32 + ((lane >> 4) << 3) + j;
        dst[i] = f2h(src[(ic * 64 + oc) * 16 + tap]);
    } else if (bid < 7328) {
        // prep_cb: split-fp16 codebook fragments
        int i = (bid - 5280) * 256 + t;
        int j = i & 7, lane = (i >> 3) & 63;
        int f = (i >> 9) & 63;
        int q = i >> 15;
        int pl = q & 1; int ks = q >> 1;
        int n = (f << 4) + (lane & 15);
        int k = ks * 32 + ((lane >> 4) << 3) + j;
        float w = cb[n * 256 + k];
        if (pl == 0) cbf[i] = f2h(w);
        else         cbf[i] = f2h((w - h2f(f2h(w))) * 4096.f);
    } else if (bid < 7332) {
        // prep_cbn: codebook row norms
        int row = (bid - 7328) * 256 + t;
        float s = 0.f;
        for (int c = 0; c < 256; c += 4) {
            f32x4 v = *(const f32x4*)&cb[row * 256 + c];
            s = fmaf(v.x, v.x, s); s = fmaf(v.y, v.y, s);
            s = fmaf(v.z, v.z, s); s = fmaf(v.w, v.w, s);
        }
        cbn[row] = s;
    } else {
        if (t == 0) *diff = 0.f;
    }
}

// ============================ conv1: 1->64, 5x5 s2 p2, relu, split-fp16 out ============================
__launch_bounds__(256)
__global__ void conv1_k(const float* __restrict__ x, const float* __restrict__ w,
                        const float* __restrict__ b, u16* __restrict__ oh, u16* __restrict__ ol) {
    __shared__ float wl[25 * 64];
    __shared__ float bl[64];
    int t = threadIdx.x;
    for (int i = t; i < 1600; i += 256) wl[(i % 25) * 64 + i / 25] = w[i];
    if (t < 64) bl[t] = b[t];
    __syncthreads();
    int p = blockIdx.x * 256 + t;                       // 262144 pixels
    int ox = p & 63, oy = (p >> 6) & 63, n = p >> 12;
    f32x4 acc[16];
    #pragma unroll
    for (int c = 0; c < 16; ++c) acc[c] = *(f32x4*)&bl[c * 4];
    for (int dy = 0; dy < 5; ++dy) {
        int iy = 2 * oy - 2 + dy;
        if ((unsigned)iy >= 128u) continue;
        for (int dx = 0; dx < 5; ++dx) {
            int ix = 2 * ox - 2 + dx;
            if ((unsigned)ix >= 128u) continue;
            float v = x[(n * 128 + iy) * 128 + ix];
            const float* wp = &wl[(dy * 5 + dx) * 64];
            #pragma unroll
            for (int c = 0; c < 16; ++c) {
                f32x4 w4 = *(const f32x4*)&wp[c * 4];
                acc[c].x = fmaf(v, w4.x, acc[c].x); acc[c].y = fmaf(v, w4.y, acc[c].y);
                acc[c].z = fmaf(v, w4.z, acc[c].z); acc[c].w = fmaf(v, w4.w, acc[c].w);
            }
        }
    }
    #pragma unroll
    for (int c = 0; c < 16; ++c) {
        ushort4 uh, ul;
        float vv[4] = {acc[c].x, acc[c].y, acc[c].z, acc[c].w};
        u16 rh[4], rl[4];
        #pragma unroll
        for (int k = 0; k < 4; ++k) {
            float v = fmaxf(vv[k], 0.f);
            f16 hh = (f16)v;
            rh[k] = __builtin_bit_cast(u16, hh);
            rl[k] = f2h((v - (float)hh) * 4096.f);
        }
        uh.x = rh[0]; uh.y = rh[1]; uh.z = rh[2]; uh.w = rh[3];
        ul.x = rl[0]; ul.y = rl[1]; ul.z = rl[2]; ul.w = rl[3];
        *(ushort4*)&oh[p * 64 + c * 4] = uh;
        *(ushort4*)&ol[p * 64 + c * 4] = ul;
    }
}

// ============================ conv2: 16x16 tile, waves partition PIXELS, 3 blocks/CU ============================
// Occupancy push: nc-outer B loading cuts live regs (B 32->16) so __launch_bounds__(256,3) fits
// 170-VGPR budget -> 3 waves/SIMD (was 2). A LDS reads double (8->16/tap/wave) but at 3 blocks/CU
// all pipes stay under MFMA: LDS 2304 < MFMA 2794 cyc/tap/CU, B 1536. LDS 3x51.2KB = 153.6 <= 160KB.
__launch_bounds__(256, 3)
__global__ void conv5w_k(const u16* __restrict__ Ah_g, const u16* __restrict__ Al_g,
                         const u16* __restrict__ wBf, const float* __restrict__ bias,
                         u16* __restrict__ Oh, u16* __restrict__ Ol) {
    constexpr int PATCH = 20;                 // 16 + 4 halo (pad 2, 5x5)
    constexpr int NPIX = PATCH * PATCH;       // 400
    constexpr int PLSZ = (NPIX / 2) * 64;     // 12800 halves per plane
    __shared__ u16 patch[2 * PLSZ];           // 51200 B

    int t = threadIdx.x, l = t & 63, wv = t >> 6, g = l >> 4;
    int qy = wv >> 1, qx = wv & 1;

    int bi = blockIdx.x;
    int wlin = (bi & 7) * ((int)gridDim.x >> 3) + (bi >> 3);   // XCD slab
    int txi = wlin & 3; int rest = wlin >> 2;
    int tyi = rest & 3; int n = rest >> 2;
    int iy0 = (tyi << 4) - 2, ix0 = (txi << 4) - 2;

    int ppb[4];
    #pragma unroll
    for (int mi = 0; mi < 4; ++mi) {
        int m = mi * 16 + (l & 15);
        ppb[mi] = ((qy << 3) + (m >> 3)) * PATCH + (qx << 3) + (m & 7);
    }

    f32x4 acc0[4][4], acc1[4][4];
    f32x4 z4 = {0.f, 0.f, 0.f, 0.f};
    #pragma unroll
    for (int mi = 0; mi < 4; ++mi)
        #pragma unroll
        for (int ni = 0; ni < 4; ++ni) { acc0[mi][ni] = z4; acc1[mi][ni] = z4; }

    int tap0 = bi % 25;
    int dy0 = tap0 / 5, dx0 = tap0 - 5 * dy0;
    int tadd0 = dy0 * PATCH + dx0;
    int iccr = bi & 1;
    const size_t tstride = 16 * 512;          // 4*NF*512, NF=4

    for (int icci = 0; icci < 2; ++icci) {
        int icc = icci ^ iccr;
        __syncthreads();
        for (int i = t; i < NPIX * 8; i += 256) {
            int c = i & 3; int r2 = i >> 2;
            int pl = (r2 >= NPIX); int pp = r2 - pl * NPIX;
            int py = pp / PATCH, px = pp - py * PATCH;
            int iy = iy0 + py, ix = ix0 + px;
            uint4 v = make_uint4(0u, 0u, 0u, 0u);
            if ((unsigned)iy < 64u && (unsigned)ix < 64u)
                v = *(const uint4*)&(pl ? Al_g : Ah_g)[(((n * 64 + iy) * 64 + ix)) * 64 + icc * 32 + c * 8];
            int P = pp >> 1, r = pp & 1;
            int slot = (r << 2) | ((c + P) & 3);
            *(uint4*)&patch[pl * PLSZ + (P << 6) + (slot << 3)] = v;
        }
        __syncthreads();

        const u16* pB = wBf + (size_t)((tap0 * 4 + icc * 2) * 4) * 512 + l * 8;
        int tap = tap0, dx = dx0, tadd = tadd0;
        for (int tapi = 0; tapi < 25; ++tapi) {
            #pragma unroll
            for (int nc = 0; nc < 2; ++nc) {
                f16x8 Bh0 = *(const f16x8*)&pB[(nc * 2 + 0) * 512];
                f16x8 Bh1 = *(const f16x8*)&pB[(nc * 2 + 1) * 512];
                f16x8 Bl0 = *(const f16x8*)&pB[(4 + nc * 2 + 0) * 512];
                f16x8 Bl1 = *(const f16x8*)&pB[(4 + nc * 2 + 1) * 512];
                #pragma unroll
                for (int mi = 0; mi < 4; ++mi) {
                    int pp = ppb[mi] + tadd;
                    int P = pp >> 1, r = pp & 1;
                    int offs = (P << 6) + (((r << 2) | ((g + P) & 3)) << 3);
                    f16x8 ah = *(const f16x8*)&patch[offs];
                    f16x8 al = *(const f16x8*)&patch[PLSZ + offs];
                    int n0 = nc * 2, n1 = nc * 2 + 1;
                    acc0[mi][n0] = __builtin_amdgcn_mfma_f32_16x16x32_f16(ah, Bh0, acc0[mi][n0], 0, 0, 0);
                    acc0[mi][n1] = __builtin_amdgcn_mfma_f32_16x16x32_f16(ah, Bh1, acc0[mi][n1], 0, 0, 0);
                    acc1[mi][n0] = __builtin_amdgcn_mfma_f32_16x16x32_f16(ah, Bl0, acc1[mi][n0], 0, 0, 0);
                    acc1[mi][n0] = __builtin_amdgcn_mfma_f32_16x16x32_f16(al, Bh0, acc1[mi][n0], 0, 0, 0);
                    acc1[mi][n1] = __builtin_amdgcn_mfma_f32_16x16x32_f16(ah, Bl1, acc1[mi][n1], 0, 0, 0);
                    acc1[mi][n1] = __builtin_amdgcn_mfma_f32_16x16x32_f16(al, Bh1, acc1[mi][n1], 0, 0, 0);
                }
            }
            pB = (tap == 24) ? (pB - 24 * tstride) : (pB + tstride);
            if (tap == 24) { tap = 0; dx = 0; tadd = 0; }
            else {
                tap++; dx++; tadd++;
                if (dx == 5) { dx = 0; tadd += PATCH - 5; }
            }
        }
    }
    #pragma unroll
    for (int mi = 0; mi < 4; ++mi)
        #pragma unroll
        for (int ni = 0; ni < 4; ++ni) {
            int oc = ni * 16 + (l & 15);
            float bv = bias[oc];
            #pragma unroll
            for (int reg = 0; reg < 4; ++reg) {
                float v = acc0[mi][ni][reg] + acc1[mi][ni][reg] * (1.f / 4096.f) + bv;
                v = fmaxf(v, 0.f);
                int pix = mi * 16 + g * 4 + reg;
                int oy = (tyi << 4) + (qy << 3) + (pix >> 3);
                int ox = (txi << 4) + (qx << 3) + (pix & 7);
                int idx = ((n * 64 + oy) * 64 + ox) * 64 + oc;
                f16 hh = (f16)v;
                Oh[idx] = __builtin_bit_cast(u16, hh);
                Ol[idx] = f2h((v - (float)hh) * 4096.f);
            }
        }
}

// ============================ conv3: S=2, 8x8 tile, 512 thr / 8 waves, M=4/N=2 (R9-measured) ============================
__launch_bounds__(512, 4)
__global__ void conv5x_k(const u16* __restrict__ Ah_g, const u16* __restrict__ Al_g,
                         const u16* __restrict__ wBf, const float* __restrict__ bias,
                         u16* __restrict__ Oh, u16* __restrict__ Ol) {
    constexpr int PATCH = 19;                 // 8*2 + 3 halo (pad 2, 5x5, s2)
    constexpr int NPIX = PATCH * PATCH;       // 361
    constexpr int NPAIR = (NPIX + 1) / 2;     // 181
    constexpr int PLSZ = NPAIR * 64;          // 11584 halves per plane
    __shared__ u16 patch[2 * PLSZ];           // 46336 B

    int t = threadIdx.x, l = t & 63, wv = t >> 6, g = l >> 4;

    int bi = blockIdx.x;
    int wlin = (bi & 7) * ((int)gridDim.x >> 3) + (bi >> 3);   // XCD slab
    int txi = wlin & 3; int rest = wlin >> 2;
    int tyi = rest & 3; int n = rest >> 2;
    int iy0 = ((tyi << 3) << 1) - 2, ix0 = ((txi << 3) << 1) - 2;

    int ppb[4];
    #pragma unroll
    for (int mi = 0; mi < 4; ++mi) {
        int m = mi * 16 + (l & 15);
        ppb[mi] = (2 * (m >> 3)) * PATCH + 2 * (m & 7);
    }

    f32x4 acc0[4][2], acc1[4][2];
    f32x4 z4 = {0.f, 0.f, 0.f, 0.f};
    #pragma unroll
    for (int mi = 0; mi < 4; ++mi)
        #pragma unroll
        for (int ni = 0; ni < 2; ++ni) { acc0[mi][ni] = z4; acc1[mi][ni] = z4; }

    int tap0 = bi % 25;
    int dy0 = tap0 / 5, dx0 = tap0 - 5 * dy0;
    int tadd0 = dy0 * PATCH + dx0;
    int iccr = bi & 1;
    int fg = __builtin_amdgcn_readfirstlane(wv * 2);       // oc-eighth base (frag units of 16)
    const size_t tstride = (size_t)(4 * 16) * 512;         // 32768

    for (int icci = 0; icci < 2; ++icci) {
        int icc = icci ^ iccr;
        __syncthreads();
        for (int i = t; i < NPIX * 8; i += 512) {
            int c = i & 3; int r2 = i >> 2;
            int pl = (r2 >= NPIX); int pp = r2 - pl * NPIX;
            int py = pp / PATCH, px = pp - py * PATCH;
            int iy = iy0 + py, ix = ix0 + px;
            uint4 v = make_uint4(0u, 0u, 0u, 0u);
            if ((unsigned)iy < 64u && (unsigned)ix < 64u)
                v = *(const uint4*)&(pl ? Al_g : Ah_g)[(((n * 64 + iy) * 64 + ix)) * 64 + icc * 32 + c * 8];
            int P = pp >> 1, r = pp & 1;
            *(uint4*)&patch[pl * PLSZ + (P << 6) + (slotf(P, c, r) << 3)] = v;
        }
        __syncthreads();

        const u16* pB = wBf + (size_t)((tap0 * 4 + icc * 2) * 16 + fg) * 512 + l * 8;
        int tap = tap0, dx = dx0, tadd = tadd0;
        for (int tapi = 0; tapi < 25; ++tapi) {
            f16x8 Bh0 = *(const f16x8*)&pB[0 * 512];
            f16x8 Bh1 = *(const f16x8*)&pB[1 * 512];
            f16x8 Bl0 = *(const f16x8*)&pB[16 * 512];
            f16x8 Bl1 = *(const f16x8*)&pB[17 * 512];
            #pragma unroll
            for (int mi = 0; mi < 4; ++mi) {
                int pp = ppb[mi] + tadd;
                int P = pp >> 1, r = pp & 1;
                int offs = (P << 6) + (slotf(P, g, r) << 3);
                f16x8 ah = *(const f16x8*)&patch[offs];
                f16x8 al = *(const f16x8*)&patch[PLSZ + offs];
                acc0[mi][0] = __builtin_amdgcn_mfma_f32_16x16x32_f16(ah, Bh0, acc0[mi][0], 0, 0, 0);
                acc0[mi][1] = __builtin_amdgcn_mfma_f32_16x16x32_f16(ah, Bh1, acc0[mi][1], 0, 0, 0);
                acc1[mi][0] = __builtin_amdgcn_mfma_f32_16x16x32_f16(ah, Bl0, acc1[mi][0], 0, 0, 0);
                acc1[mi][0] = __builtin_amdgcn_mfma_f32_16x16x32_f16(al, Bh0, acc1[mi][0], 0, 0, 0);
                acc1[mi][1] = __builtin_amdgcn_mfma_f32_16x16x32_f16(ah, Bl1, acc1[mi][1], 0, 0, 0);
                acc1[mi][1] = __builtin_amdgcn_mfma_f32_16x16x32_f16(al, Bh1, acc1[mi][1], 0, 0, 0);
            }
            pB = (tap == 24) ? (pB - 24 * tstride) : (pB + tstride);
            if (tap == 24) { tap = 0; dx = 0; tadd = 0; }
            else {
                tap++; dx++; tadd++;
                if (dx == 5) { dx = 0; tadd += PATCH - 5; }
            }
        }
    }
    #pragma unroll
    for (int mi = 0; mi < 4; ++mi)
        #pragma unroll
        for (int ni = 0; ni < 2; ++ni) {
            int oc = (fg + ni) * 16 + (l & 15);
            float bv = bias[oc];
            #pragma unroll
            for (int reg = 0; reg < 4; ++reg) {
                float v = acc0[mi][ni][reg] + acc1[mi][ni][reg] * (1.f / 4096.f) + bv;
                int pix = mi * 16 + g * 4 + reg;
                int oy = (tyi << 3) + (pix >> 3), ox = (txi << 3) + (pix & 7);
                int idx = ((n * 32 + oy) * 32 + ox) * 256 + oc;
                f16 hh = (f16)v;
                Oh[idx] = __builtin_bit_cast(u16, hh);
                Ol[idx] = f2h((v - (float)hh) * 4096.f);
            }
        }
}

// ============================ quantize v4: A-in-registers, B via LDS double-buffer ============================
__launch_bounds__(256, 2)
__global__ void quant_k(const u16* __restrict__ zh, const u16* __restrict__ zl,
                        const u16* __restrict__ cbf, const float* __restrict__ cbn,
                        const float* __restrict__ cb, u16* __restrict__ e,
                        float* __restrict__ diff) {
    __shared__ u16 Bbuf[2 * 32 * 512];     // [buf][ks*4+pl*2+nf][lane*8]
    __shared__ float cbn_l[1024];
    __shared__ float zn_l[128];
    __shared__ float bd_l[128];
    __shared__ int   wi_l[128];

    int t = threadIdx.x, l = t & 63, wv = t >> 6, g = l >> 4;
    int bi = blockIdx.x;
    int row0 = bi << 7;

    {
        f32x4 v = *(const f32x4*)&cbn[t * 4];
        *(f32x4*)&cbn_l[t * 4] = v;
    }

    f16x8 Ah[2][8], Al[2][8];
    int rbase = row0 + wv * 32 + (l & 15);
    #pragma unroll
    for (int mi = 0; mi < 2; ++mi)
        #pragma unroll
        for (int ks = 0; ks < 8; ++ks) {
            size_t off = (size_t)(rbase + mi * 16) * 256 + ks * 32 + g * 8;
            Ah[mi][ks] = *(const f16x8*)&zh[off];
            Al[mi][ks] = *(const f16x8*)&zl[off];
        }

    #pragma unroll
    for (int mi = 0; mi < 2; ++mi) {
        float s = 0.f;
        #pragma unroll
        for (int ks = 0; ks < 8; ++ks)
            #pragma unroll
            for (int j = 0; j < 8; ++j) {
                float v = (float)Ah[mi][ks][j] + (float)Al[mi][ks][j] * (1.f / 4096.f);
                s = fmaf(v, v, s);
            }
        s += __shfl_xor(s, 16);
        s += __shfl_xor(s, 32);
        if (g == 0) zn_l[wv * 32 + mi * 16 + (l & 15)] = s;
    }

    float rd[8]; int rc[8];
    #pragma unroll
    for (int s = 0; s < 8; ++s) { rd[s] = 1e30f; rc[s] = 0; }

    int fi = wv * 8;
    {
        int no0 = bi & 31;
        #pragma unroll
        for (int q = 0; q < 8; ++q) {
            int f2 = fi + q;
            int ks = f2 >> 2, pl = (f2 >> 1) & 1, nf = f2 & 1;
            f16x8 v = *(const f16x8*)&cbf[(size_t)(((ks * 2 + pl) * 64) + no0 * 2 + nf) * 512 + l * 8];
            *(uint4*)&Bbuf[(size_t)f2 * 512 + l * 8] = __builtin_bit_cast(uint4, v);
        }
    }
    __syncthreads();

    for (int noi = 0; noi < 32; ++noi) {
        int b = noi & 1;
        int no_cur = (noi + bi) & 31;

        f16x8 pf[8];
        if (noi < 31) {
            int no_n = (noi + 1 + bi) & 31;
            #pragma unroll
            for (int q = 0; q < 8; ++q) {
                int f2 = fi + q;
                int ks = f2 >> 2, pl = (f2 >> 1) & 1, nf = f2 & 1;
                pf[q] = *(const f16x8*)&cbf[(size_t)(((ks * 2 + pl) * 64) + no_n * 2 + nf) * 512 + l * 8];
            }
        }

        f32x4 acc0[2][2], acc1[2][2];
        f32x4 z4 = {0.f, 0.f, 0.f, 0.f};
        #pragma unroll
        for (int mi = 0; mi < 2; ++mi)
            #pragma unroll
            for (int nf = 0; nf < 2; ++nf) { acc0[mi][nf] = z4; acc1[mi][nf] = z4; }

        #pragma unroll
        for (int ks = 0; ks < 8; ++ks) {
            const u16* bb = &Bbuf[(size_t)(b * 32 + ks * 4) * 512 + l * 8];
            f16x8 Bh0 = *(const f16x8*)&bb[0 * 512];
            f16x8 Bh1 = *(const f16x8*)&bb[1 * 512];
            f16x8 Bl0 = *(const f16x8*)&bb[2 * 512];
            f16x8 Bl1 = *(const f16x8*)&bb[3 * 512];
            #pragma unroll
            for (int mi = 0; mi < 2; ++mi) {
                acc0[mi][0] = __builtin_amdgcn_mfma_f32_16x16x32_f16(Ah[mi][ks], Bh0, acc0[mi][0], 0, 0, 0);
                acc0[mi][1] = __builtin_amdgcn_mfma_f32_16x16x32_f16(Ah[mi][ks], Bh1, acc0[mi][1], 0, 0, 0);
                acc1[mi][0] = __builtin_amdgcn_mfma_f32_16x16x32_f16(Ah[mi][ks], Bl0, acc1[mi][0], 0, 0, 0);
                acc1[mi][0] = __builtin_amdgcn_mfma_f32_16x16x32_f16(Al[mi][ks], Bh0, acc1[mi][0], 0, 0, 0);
                acc1[mi][1] = __builtin_amdgcn_mfma_f32_16x16x32_f16(Ah[mi][ks], Bl1, acc1[mi][1], 0, 0, 0);
                acc1[mi][1] = __builtin_amdgcn_mfma_f32_16x16x32_f16(Al[mi][ks], Bh1, acc1[mi][1], 0, 0, 0);
            }
        }

        #pragma unroll
        for (int nf = 0; nf < 2; ++nf) {
            int col = no_cur * 32 + nf * 16 + (l & 15);
            float cn = cbn_l[col];
            #pragma unroll
            for (int mi = 0; mi < 2; ++mi)
                #pragma unroll
                for (int reg = 0; reg < 4; ++reg) {
                    float d = cn - 2.f * (acc0[mi][nf][reg] + acc1[mi][nf][reg] * (1.f / 4096.f));
                    int slot = mi * 4 + reg;
                    if (d < rd[slot] || (d == rd[slot] && col < rc[slot])) { rd[slot] = d; rc[slot] = col; }
                }
        }

        if (noi < 31) {
            #pragma unroll
            for (int q = 0; q < 8; ++q)
                *(uint4*)&Bbuf[(size_t)((1 - b) * 32 + fi + q) * 512 + l * 8] = __builtin_bit_cast(uint4, pf[q]);
        }
        __syncthreads();
    }

    #pragma unroll
    for (int step = 1; step < 16; step <<= 1) {
        #pragma unroll
        for (int s = 0; s < 8; ++s) {
            float od = __shfl_xor(rd[s], step);
            int ocl = __shfl_xor(rc[s], step);
            if (od < rd[s] || (od == rd[s] && ocl < rc[s])) { rd[s] = od; rc[s] = ocl; }
        }
    }
    if ((l & 15) == 0) {
        #pragma unroll
        for (int s = 0; s < 8; ++s) {
            int mi = s >> 2, reg = s & 3;
            int row = wv * 32 + mi * 16 + g * 4 + reg;
            bd_l[row] = rd[s]; wi_l[row] = rc[s];
        }
    }
    __syncthreads();
    if (t < 64) {
        float dval = (zn_l[t] + bd_l[t]) + (zn_l[t + 64] + bd_l[t + 64]);
        #pragma unroll
        for (int step = 1; step < 64; step <<= 1) dval += __shfl_xor(dval, step);
        if (t == 0) atomicAdd(diff, dval * (1.f / 16777216.f));
    }
    __syncthreads();
    // e-write: 4 independent load->store chains in flight (was 1 serial chain)
    for (int r = 0; r < 128; r += 4) {
        int wiA = wi_l[r], wiB = wi_l[r + 1], wiC = wi_l[r + 2], wiD = wi_l[r + 3];
        float vA = cb[wiA * 256 + t];
        float vB = cb[wiB * 256 + t];
        float vC = cb[wiC * 256 + t];
        float vD = cb[wiD * 256 + t];
        e[(size_t)(row0 + r) * 256 + t]     = f2h(vA);
        e[(size_t)(row0 + r + 1) * 256 + t] = f2h(vB);
        e[(size_t)(row0 + r + 2) * 256 + t] = f2h(vC);
        e[(size_t)(row0 + r + 3) * 256 + t] = f2h(vD);
    }
}

// ============================ deconv k4 s2 p1, ALL 4 PARITIES per block ============================
template<int ICT>
__launch_bounds__(256)
__global__ void deconv4m_k(const u16* __restrict__ in, const u16* __restrict__ wdf,
                           const float* __restrict__ bias, u16* __restrict__ out,
                           int IH, int IW) {
    constexpr int ICC = ICT / 32;
    constexpr int RST = ICT + 8;              // halves per pixel line
    constexpr int CHK = ICT / 8;              // uint4 chunks per pixel
    __shared__ u16 patch[100 * RST];

    int t = threadIdx.x, l = t & 63, wv = t >> 6;
    int wm = wv >> 1, wn = wv & 1, g = l >> 4;

    int bi = blockIdx.x;
    int wlin = (bi & 7) * ((int)gridDim.x >> 3) + (bi >> 3);
    int tw = IW >> 3, th = IH >> 3;
    int txi = wlin % tw; int rest = wlin / tw;
    int tyi = rest % th; int n = rest / th;
    int a0 = tyi << 3, b0 = txi << 3;
    int OH = IH << 1, OW = IW << 1;

    // stage 10x10 window rows a0-1..a0+8, cols b0-1..b0+8, all ICT channels
    for (int i = t; i < 100 * CHK; i += 256) {
        int c = i % CHK; int pp = i / CHK;
        int pr = pp / 10, pc = pp - pr * 10;
        int ar = a0 - 1 + pr, ac = b0 - 1 + pc;
        uint4 v = make_uint4(0u, 0u, 0u, 0u);
        if ((unsigned)ar < (unsigned)IH && (unsigned)ac < (unsigned)IW)
            v = *(const uint4*)&in[((size_t)(n * IH + ar) * IW + ac) * ICT + c * 8];
        *(uint4*)&patch[(pr * 10 + pc) * RST + c * 8] = v;
    }
    __syncthreads();

    int pb0[2];
    #pragma unroll
    for (int mi = 0; mi < 2; ++mi) {
        int m = wm * 32 + mi * 16 + (l & 15);
        pb0[mi] = ((m >> 3) * 10 + (m & 7)) * RST + g * 8;
    }

    float bv[2];
    #pragma unroll
    for (int ni = 0; ni < 2; ++ni) bv[ni] = bias[wn * 32 + ni * 16 + (l & 15)];

    auto ldB = [&](int par, int icc, int tt, f16x8* B) {
        int ry = par >> 1, rx = par & 1;
        int tty = tt >> 1, ttx = tt & 1;
        int tap = (1 - ry + 2 * tty) * 4 + (1 - rx + 2 * ttx);
        #pragma unroll
        for (int ni = 0; ni < 2; ++ni)
            B[ni] = *(const f16x8*)&wdf[(size_t)((tap * ICC + icc) * 4 + wn * 2 + ni) * 512 + l * 8];
    };

    constexpr int NSTEP = 4 * ICC * 4;
    constexpr int ICSH = (ICC == 2) ? 1 : 3;

    f16x8 B0[2], B1[2];
    ldB(0, 0, 0, B0);

    for (int par = 0; par < 4; ++par) {
        int ry = par >> 1, rx = par & 1;
        f32x4 acc[2][2];
        f32x4 z4 = {0.f, 0.f, 0.f, 0.f};
        #pragma unroll
        for (int mi = 0; mi < 2; ++mi)
            #pragma unroll
            for (int ni = 0; ni < 2; ++ni) acc[mi][ni] = z4;

        for (int icc = 0; icc < ICC; ++icc) {
            #pragma unroll
            for (int tt = 0; tt < 4; ++tt) {
                int s1 = ((par * ICC + icc) << 2) + tt + 1;
                if (s1 < NSTEP) {
                    int tn = s1 & 3;
                    int in_ = (s1 >> 2) & (ICC - 1);
                    int pn = s1 >> (2 + ICSH);
                    ldB(pn, in_, tn, B1);
                }
                int tty = tt >> 1, ttx = tt & 1;
                int shift = ((1 - tty + ry) * 10 + (1 - ttx + rx)) * RST + icc * 32;
                #pragma unroll
                for (int mi = 0; mi < 2; ++mi) {
                    f16x8 a = *(const f16x8*)&patch[pb0[mi] + shift];
                    #pragma unroll
                    for (int ni = 0; ni < 2; ++ni)
                        acc[mi][ni] = __builtin_amdgcn_mfma_f32_16x16x32_f16(a, B0[ni], acc[mi][ni], 0, 0, 0);
                }
                B0[0] = B1[0]; B0[1] = B1[1];
            }
        }
        #pragma unroll
        for (int mi = 0; mi < 2; ++mi)
            #pragma unroll
            for (int ni = 0; ni < 2; ++ni) {
                int oc = wn * 32 + ni * 16 + (l & 15);
                #pragma unroll
                for (int reg = 0; reg < 4; ++reg) {
                    float v = fmaxf(acc[mi][ni][reg] + bv[ni], 0.f);
                    int pix = wm * 32 + mi * 16 + g * 4 + reg;
                    int oy = ((a0 + (pix >> 3)) << 1) + ry;
                    int ox = ((b0 + (pix & 7)) << 1) + rx;
                    out[((size_t)(n * OH + oy) * OW + ox) * 64 + oc] = f2h(v);
                }
            }
    }
}

// ============================ final conv 3x3 64->1, p1, tanh (LDS-tiled, v_dot2) ============================
__launch_bounds__(256)
__global__ void conv3x3_tanh_k(const u16* __restrict__ in, const float* __restrict__ w,
                               const float* __restrict__ b, float* __restrict__ out) {
    __shared__ u16 tile[18 * 18 * 72];
    __shared__ u32 wpk[288];   // [tap][icp] half2-packed weights
    int t = threadIdx.x;
    int bi = blockIdx.x;
    int wlin = (bi & 7) * ((int)gridDim.x >> 3) + (bi >> 3);
    int n = wlin >> 6;
    int tile6 = wlin & 63;
    int ty0 = (tile6 >> 3) << 4, tx0 = (tile6 & 7) << 4;

    for (int i = t; i < 288; i += 256) {
        int tap = i >> 5, icp = i & 31;
        h2 p;
        p.x = (f16)w[(2 * icp) * 9 + tap];
        p.y = (f16)w[(2 * icp + 1) * 9 + tap];
        wpk[tap * 32 + icp] = __builtin_bit_cast(u32, p);
    }
    for (int i = t; i < 2592; i += 256) {
        int ch = i & 7, pix = i >> 3;
        int pr = pix / 18, pc = pix - pr * 18;
        int gy = ty0 - 1 + pr, gx = tx0 - 1 + pc;
        uint4 v = make_uint4(0u, 0u, 0u, 0u);
        if ((unsigned)gy < 128u && (unsigned)gx < 128u)
            v = *(const uint4*)&in[(((n << 7) + gy) * 128 + gx) * 64 + ch * 8];
        *(uint4*)&tile[pix * 72 + ch * 8] = v;
    }
    __syncthreads();

    int ty = t >> 4, tx = t & 15;
    float acc = b[0];
    #pragma unroll
    for (int dy = 0; dy < 3; ++dy) {
        #pragma unroll
        for (int dx = 0; dx < 3; ++dx) {
            int base = ((ty + dy) * 18 + (tx + dx)) * 72;
            const u32* wp = &wpk[(dy * 3 + dx) * 32];
            #pragma unroll
            for (int c8 = 0; c8 < 8; ++c8) {
                uint4 v = *(const uint4*)&tile[base + c8 * 8];
                acc = __builtin_amdgcn_fdot2(__builtin_bit_cast(h2, v.x),
                        __builtin_bit_cast(h2, wp[c8 * 4 + 0]), acc, false);
                acc = __builtin_amdgcn_fdot2(__builtin_bit_cast(h2, v.y),
                        __builtin_bit_cast(h2, wp[c8 * 4 + 1]), acc, false);
                acc = __builtin_amdgcn_fdot2(__builtin_bit_cast(h2, v.z),
                        __builtin_bit_cast(h2, wp[c8 * 4 + 2]), acc, false);
                acc = __builtin_amdgcn_fdot2(__builtin_bit_cast(h2, v.w),
                        __builtin_bit_cast(h2, wp[c8 * 4 + 3]), acc, false);
            }
        }
    }
    int oy = ty0 + ty, ox = tx0 + tx;
    out[(n << 14) + (oy << 7) + ox] = tanhf(acc);
}

extern "C" void kernel_launch(void* const* d_in, const int* in_sizes, int n_in,
                              void* d_out, int out_size, void* d_ws, size_t ws_size,
                              hipStream_t stream) {
    (void)in_sizes; (void)n_in; (void)out_size; (void)ws_size;
    const float* x   = (const float*)d_in[0];
    const float* ew1 = (const float*)d_in[1];
    const float* eb1 = (const float*)d_in[2];
    const float* ew2 = (const float*)d_in[3];
    const float* eb2 = (const float*)d_in[4];
    const float* ew3 = (const float*)d_in[5];
    const float* eb3 = (const float*)d_in[6];
    const float* cb  = (const float*)d_in[7];
    const float* dw1 = (const float*)d_in[8];
    const float* db1 = (const float*)d_in[9];
    const float* dw2 = (const float*)d_in[10];
    const float* db2 = (const float*)d_in[11];
    const float* dw3 = (const float*)d_in[12];
    const float* db3 = (const float*)d_in[13];
    float* out = (float*)d_out;

    u16* ws = (u16*)d_ws;
    u16* a1h = ws;             u16* a1l = ws + 16777216;
    u16* zh  = ws;             u16* zl  = ws + 16777216;
    u16* a2h = ws + 33554432;  u16* a2l = ws + 50331648;
    u16* e   = ws + 33554432;
    u16* y1  = ws + 67108864;
    u16* y2  = ws;
    u16* wBf2 = ws + 83886080;          // 204800
    u16* wBf3 = wBf2 + 204800;          // 819200
    u16* wd1f = wBf3 + 819200;          // 262144
    u16* wd2f = wd1f + 262144;          // 65536
    u16* cbf  = wd2f + 65536;           // 524288
    float* cbn = (float*)(cbf + 524288);

    prep_all_k<<<7333, 256, 0, stream>>>(ew2, ew3, dw1, dw2, cb,
                                         wBf2, wBf3, wd1f, wd2f, cbf, cbn,
                                         out + 1048576);

    conv1_k<<<1024, 256, 0, stream>>>(x, ew1, eb1, a1h, a1l);
    conv5w_k<<<1024, 256, 0, stream>>>(a1h, a1l, wBf2, eb2, a2h, a2l);
    conv5x_k<<<1024, 512, 0, stream>>>(a2h, a2l, wBf3, eb3, zh, zl);
    quant_k<<<512, 256, 0, stream>>>(zh, zl, cbf, cbn, cb, e, out + 1048576);
    deconv4m_k<256><<<1024, 256, 0, stream>>>(e, wd1f, db1, y1, 32, 32);
    deconv4m_k<64><<<4096, 256, 0, stream>>>(y1, wd2f, db2, y2, 64, 64);
    conv3x3_tanh_k<<<4096, 256, 0, stream>>>(y2, dw3, db3, out);
}

// Round 11
// 622.147 us; speedup vs baseline: 1.2678x; 1.2678x over previous
//
#include <hip/hip_runtime.h>

typedef _Float16 f16;
typedef _Float16 f16x8 __attribute__((ext_vector_type(8)));
typedef _Float16 f16x4 __attribute__((ext_vector_type(4)));
typedef _Float16 h2 __attribute__((ext_vector_type(2)));
typedef float f32x4 __attribute__((ext_vector_type(4)));
typedef unsigned short u16;
typedef unsigned int u32;

#define DEVI __device__ __forceinline__

DEVI u16 f2h(float f) { f16 h = (f16)f; return __builtin_bit_cast(u16, h); }
DEVI float h2f(u16 u) { f16 h = __builtin_bit_cast(f16, u); return (float)h; }

// S-agnostic conflict-free LDS slot map: pair P holds 8 uint4 (2 pixels r=0,1 x 4 chunks c).
DEVI int slotf(int P, int c, int r) { return ((c + P) & 3) | (((r + (P >> 2)) & 1) << 2); }

// ============================ merged weight prep (one dispatch; saves 6 launch gaps) ============================
// bid ranges: [0,800) wconv ew2 | [800,4000) wconv ew3 | [4000,5024) wdec dw1 |
// [5024,5280) wdec dw2 | [5280,7328) cb | [7328,7332) cbn | 7332 diff-zero
__launch_bounds__(256)
__global__ void prep_all_k(const float* __restrict__ ew2, const float* __restrict__ ew3,
                           const float* __restrict__ dw1, const float* __restrict__ dw2,
                           const float* __restrict__ cb,
                           u16* __restrict__ wBf2, u16* __restrict__ wBf3,
                           u16* __restrict__ wd1f, u16* __restrict__ wd2f,
                           u16* __restrict__ cbf, float* __restrict__ cbn,
                           float* __restrict__ diff) {
    int bid = blockIdx.x, t = threadIdx.x;
    if (bid < 4000) {
        // prep_wconv: split-fp16 conv weights
        const float* src; u16* dst; int nf_sh, i;
        if (bid < 800) { src = ew2; dst = wBf2; nf_sh = 2; i = bid * 256 + t; }
        else           { src = ew3; dst = wBf3; nf_sh = 4; i = (bid - 800) * 256 + t; }
        int j = i & 7, lane = (i >> 3) & 63;
        int q = i >> 9;
        int f = q & ((1 << nf_sh) - 1); q >>= nf_sh;
        int pl = q & 1; q >>= 1;
        int icc = q & 1; int tap = q >> 1;
        int oc = (f << 4) + (lane & 15);
        int ic = icc * 32 + ((lane >> 4) << 3) + j;
        float w = src[(oc * 64 + ic) * 25 + tap];
        if (pl == 0) dst[i] = f2h(w);
        else         dst[i] = f2h((w - h2f(f2h(w))) * 4096.f);
    } else if (bid < 5280) {
        // prep_wdec: deconv weights
        const float* src; u16* dst; int icc_sh, i;
        if (bid < 5024) { src = dw1; dst = wd1f; icc_sh = 3; i = (bid - 4000) * 256 + t; }
        else            { src = dw2; dst = wd2f; icc_sh = 1; i = (bid - 5024) * 256 + t; }
        int j = i & 7, lane = (i >> 3) & 63;
        int f = (i >> 9) & 3;
        int q = i >> 11;
        int icc = q & ((1 << icc_sh) - 1); int tap = q >> icc_sh;
        int oc = (f << 4) + (lane & 15);
        int ic = icc * 32 + ((lane >> 4) << 3) + j;
        dst[i] = f2h(src[(ic * 64 + oc) * 16 + tap]);
    } else if (bid < 7328) {
        // prep_cb: split-fp16 codebook fragments
        int i = (bid - 5280) * 256 + t;
        int j = i & 7, lane = (i >> 3) & 63;
        int f = (i >> 9) & 63;
        int q = i >> 15;
        int pl = q & 1; int ks = q >> 1;
        int n = (f << 4) + (lane & 15);
        int k = ks * 32 + ((lane >> 4) << 3) + j;
        float w = cb[n * 256 + k];
        if (pl == 0) cbf[i] = f2h(w);
        else         cbf[i] = f2h((w - h2f(f2h(w))) * 4096.f);
    } else if (bid < 7332) {
        // prep_cbn: codebook row norms
        int row = (bid - 7328) * 256 + t;
        float s = 0.f;
        for (int c = 0; c < 256; c += 4) {
            f32x4 v = *(const f32x4*)&cb[row * 256 + c];
            s = fmaf(v.x, v.x, s); s = fmaf(v.y, v.y, s);
            s = fmaf(v.z, v.z, s); s = fmaf(v.w, v.w, s);
        }
        cbn[row] = s;
    } else {
        if (t == 0) *diff = 0.f;
    }
}

// ============================ conv1: 1->64, 5x5 s2 p2, relu, split-fp16 out ============================
__launch_bounds__(256)
__global__ void conv1_k(const float* __restrict__ x, const float* __restrict__ w,
                        const float* __restrict__ b, u16* __restrict__ oh, u16* __restrict__ ol) {
    __shared__ float wl[25 * 64];
    __shared__ float bl[64];
    int t = threadIdx.x;
    for (int i = t; i < 1600; i += 256) wl[(i % 25) * 64 + i / 25] = w[i];
    if (t < 64) bl[t] = b[t];
    __syncthreads();
    int p = blockIdx.x * 256 + t;                       // 262144 pixels
    int ox = p & 63, oy = (p >> 6) & 63, n = p >> 12;
    f32x4 acc[16];
    #pragma unroll
    for (int c = 0; c < 16; ++c) acc[c] = *(f32x4*)&bl[c * 4];
    for (int dy = 0; dy < 5; ++dy) {
        int iy = 2 * oy - 2 + dy;
        if ((unsigned)iy >= 128u) continue;
        for (int dx = 0; dx < 5; ++dx) {
            int ix = 2 * ox - 2 + dx;
            if ((unsigned)ix >= 128u) continue;
            float v = x[(n * 128 + iy) * 128 + ix];
            const float* wp = &wl[(dy * 5 + dx) * 64];
            #pragma unroll
            for (int c = 0; c < 16; ++c) {
                f32x4 w4 = *(const f32x4*)&wp[c * 4];
                acc[c].x = fmaf(v, w4.x, acc[c].x); acc[c].y = fmaf(v, w4.y, acc[c].y);
                acc[c].z = fmaf(v, w4.z, acc[c].z); acc[c].w = fmaf(v, w4.w, acc[c].w);
            }
        }
    }
    #pragma unroll
    for (int c = 0; c < 16; ++c) {
        ushort4 uh, ul;
        float vv[4] = {acc[c].x, acc[c].y, acc[c].z, acc[c].w};
        u16 rh[4], rl[4];
        #pragma unroll
        for (int k = 0; k < 4; ++k) {
            float v = fmaxf(vv[k], 0.f);
            f16 hh = (f16)v;
            rh[k] = __builtin_bit_cast(u16, hh);
            rl[k] = f2h((v - (float)hh) * 4096.f);
        }
        uh.x = rh[0]; uh.y = rh[1]; uh.z = rh[2]; uh.w = rh[3];
        ul.x = rl[0]; ul.y = rl[1]; ul.z = rl[2]; ul.w = rl[3];
        *(ushort4*)&oh[p * 64 + c * 4] = uh;
        *(ushort4*)&ol[p * 64 + c * 4] = ul;
    }
}

// ============================ conv2: 16x16 tile, waves partition PIXELS (R5-measured version) ============================
__launch_bounds__(256, 2)
__global__ void conv5w_k(const u16* __restrict__ Ah_g, const u16* __restrict__ Al_g,
                         const u16* __restrict__ wBf, const float* __restrict__ bias,
                         u16* __restrict__ Oh, u16* __restrict__ Ol) {
    constexpr int PATCH = 20;                 // 16 + 4 halo (pad 2, 5x5)
    constexpr int NPIX = PATCH * PATCH;       // 400
    constexpr int PLSZ = (NPIX / 2) * 64;     // 12800 halves per plane
    __shared__ u16 patch[2 * PLSZ];           // 51200 B

    int t = threadIdx.x, l = t & 63, wv = t >> 6, g = l >> 4;
    int qy = wv >> 1, qx = wv & 1;

    int bi = blockIdx.x;
    int wlin = (bi & 7) * ((int)gridDim.x >> 3) + (bi >> 3);   // XCD slab
    int txi = wlin & 3; int rest = wlin >> 2;
    int tyi = rest & 3; int n = rest >> 2;
    int iy0 = (tyi << 4) - 2, ix0 = (txi << 4) - 2;

    int ppb[4];
    #pragma unroll
    for (int mi = 0; mi < 4; ++mi) {
        int m = mi * 16 + (l & 15);
        ppb[mi] = ((qy << 3) + (m >> 3)) * PATCH + (qx << 3) + (m & 7);
    }

    f32x4 acc0[4][4], acc1[4][4];
    f32x4 z4 = {0.f, 0.f, 0.f, 0.f};
    #pragma unroll
    for (int mi = 0; mi < 4; ++mi)
        #pragma unroll
        for (int ni = 0; ni < 4; ++ni) { acc0[mi][ni] = z4; acc1[mi][ni] = z4; }

    int tap0 = bi % 25;
    int dy0 = tap0 / 5, dx0 = tap0 - 5 * dy0;
    int tadd0 = dy0 * PATCH + dx0;
    int iccr = bi & 1;
    const size_t tstride = 16 * 512;          // 4*NF*512, NF=4

    for (int icci = 0; icci < 2; ++icci) {
        int icc = icci ^ iccr;
        __syncthreads();
        for (int i = t; i < NPIX * 8; i += 256) {
            int c = i & 3; int r2 = i >> 2;
            int pl = (r2 >= NPIX); int pp = r2 - pl * NPIX;
            int py = pp / PATCH, px = pp - py * PATCH;
            int iy = iy0 + py, ix = ix0 + px;
            uint4 v = make_uint4(0u, 0u, 0u, 0u);
            if ((unsigned)iy < 64u && (unsigned)ix < 64u)
                v = *(const uint4*)&(pl ? Al_g : Ah_g)[(((n * 64 + iy) * 64 + ix)) * 64 + icc * 32 + c * 8];
            int P = pp >> 1, r = pp & 1;
            int slot = (r << 2) | ((c + P) & 3);
            *(uint4*)&patch[pl * PLSZ + (P << 6) + (slot << 3)] = v;
        }
        __syncthreads();

        const u16* pB = wBf + (size_t)((tap0 * 4 + icc * 2) * 4) * 512 + l * 8;
        int tap = tap0, dx = dx0, tadd = tadd0;
        for (int tapi = 0; tapi < 25; ++tapi) {
            f16x8 Bh[4], Bl[4];
            #pragma unroll
            for (int ni = 0; ni < 4; ++ni) {
                Bh[ni] = *(const f16x8*)&pB[ni * 512];
                Bl[ni] = *(const f16x8*)&pB[(4 + ni) * 512];
            }
            #pragma unroll
            for (int mi = 0; mi < 4; ++mi) {
                int pp = ppb[mi] + tadd;
                int P = pp >> 1, r = pp & 1;
                int offs = (P << 6) + (((r << 2) | ((g + P) & 3)) << 3);
                f16x8 ah = *(const f16x8*)&patch[offs];
                f16x8 al = *(const f16x8*)&patch[PLSZ + offs];
                #pragma unroll
                for (int ni = 0; ni < 4; ++ni) {
                    acc0[mi][ni] = __builtin_amdgcn_mfma_f32_16x16x32_f16(ah, Bh[ni], acc0[mi][ni], 0, 0, 0);
                    acc1[mi][ni] = __builtin_amdgcn_mfma_f32_16x16x32_f16(ah, Bl[ni], acc1[mi][ni], 0, 0, 0);
                    acc1[mi][ni] = __builtin_amdgcn_mfma_f32_16x16x32_f16(al, Bh[ni], acc1[mi][ni], 0, 0, 0);
                }
            }
            pB = (tap == 24) ? (pB - 24 * tstride) : (pB + tstride);
            if (tap == 24) { tap = 0; dx = 0; tadd = 0; }
            else {
                tap++; dx++; tadd++;
                if (dx == 5) { dx = 0; tadd += PATCH - 5; }
            }
        }
    }
    #pragma unroll
    for (int mi = 0; mi < 4; ++mi)
        #pragma unroll
        for (int ni = 0; ni < 4; ++ni) {
            int oc = ni * 16 + (l & 15);
            float bv = bias[oc];
            #pragma unroll
            for (int reg = 0; reg < 4; ++reg) {
                float v = acc0[mi][ni][reg] + acc1[mi][ni][reg] * (1.f / 4096.f) + bv;
                v = fmaxf(v, 0.f);
                int pix = mi * 16 + g * 4 + reg;
                int oy = (tyi << 4) + (qy << 3) + (pix >> 3);
                int ox = (txi << 4) + (qx << 3) + (pix & 7);
                int idx = ((n * 64 + oy) * 64 + ox) * 64 + oc;
                f16 hh = (f16)v;
                Oh[idx] = __builtin_bit_cast(u16, hh);
                Ol[idx] = f2h((v - (float)hh) * 4096.f);
            }
        }
}

// ============================ conv3: S=2, 8x8 tile, 512 thr / 8 waves, M=4/N=2 (R9-measured) ============================
__launch_bounds__(512, 4)
__global__ void conv5x_k(const u16* __restrict__ Ah_g, const u16* __restrict__ Al_g,
                         const u16* __restrict__ wBf, const float* __restrict__ bias,
                         u16* __restrict__ Oh, u16* __restrict__ Ol) {
    constexpr int PATCH = 19;                 // 8*2 + 3 halo (pad 2, 5x5, s2)
    constexpr int NPIX = PATCH * PATCH;       // 361
    constexpr int NPAIR = (NPIX + 1) / 2;     // 181
    constexpr int PLSZ = NPAIR * 64;          // 11584 halves per plane
    __shared__ u16 patch[2 * PLSZ];           // 46336 B

    int t = threadIdx.x, l = t & 63, wv = t >> 6, g = l >> 4;

    int bi = blockIdx.x;
    int wlin = (bi & 7) * ((int)gridDim.x >> 3) + (bi >> 3);   // XCD slab
    int txi = wlin & 3; int rest = wlin >> 2;
    int tyi = rest & 3; int n = rest >> 2;
    int iy0 = ((tyi << 3) << 1) - 2, ix0 = ((txi << 3) << 1) - 2;

    int ppb[4];
    #pragma unroll
    for (int mi = 0; mi < 4; ++mi) {
        int m = mi * 16 + (l & 15);
        ppb[mi] = (2 * (m >> 3)) * PATCH + 2 * (m & 7);
    }

    f32x4 acc0[4][2], acc1[4][2];
    f32x4 z4 = {0.f, 0.f, 0.f, 0.f};
    #pragma unroll
    for (int mi = 0; mi < 4; ++mi)
        #pragma unroll
        for (int ni = 0; ni < 2; ++ni) { acc0[mi][ni] = z4; acc1[mi][ni] = z4; }

    int tap0 = bi % 25;
    int dy0 = tap0 / 5, dx0 = tap0 - 5 * dy0;
    int tadd0 = dy0 * PATCH + dx0;
    int iccr = bi & 1;
    int fg = __builtin_amdgcn_readfirstlane(wv * 2);       // oc-eighth base (frag units of 16)
    const size_t tstride = (size_t)(4 * 16) * 512;         // 32768

    for (int icci = 0; icci < 2; ++icci) {
        int icc = icci ^ iccr;
        __syncthreads();
        for (int i = t; i < NPIX * 8; i += 512) {
            int c = i & 3; int r2 = i >> 2;
            int pl = (r2 >= NPIX); int pp = r2 - pl * NPIX;
            int py = pp / PATCH, px = pp - py * PATCH;
            int iy = iy0 + py, ix = ix0 + px;
            uint4 v = make_uint4(0u, 0u, 0u, 0u);
            if ((unsigned)iy < 64u && (unsigned)ix < 64u)
                v = *(const uint4*)&(pl ? Al_g : Ah_g)[(((n * 64 + iy) * 64 + ix)) * 64 + icc * 32 + c * 8];
            int P = pp >> 1, r = pp & 1;
            *(uint4*)&patch[pl * PLSZ + (P << 6) + (slotf(P, c, r) << 3)] = v;
        }
        __syncthreads();

        const u16* pB = wBf + (size_t)((tap0 * 4 + icc * 2) * 16 + fg) * 512 + l * 8;
        int tap = tap0, dx = dx0, tadd = tadd0;
        for (int tapi = 0; tapi < 25; ++tapi) {
            f16x8 Bh0 = *(const f16x8*)&pB[0 * 512];
            f16x8 Bh1 = *(const f16x8*)&pB[1 * 512];
            f16x8 Bl0 = *(const f16x8*)&pB[16 * 512];
            f16x8 Bl1 = *(const f16x8*)&pB[17 * 512];
            #pragma unroll
            for (int mi = 0; mi < 4; ++mi) {
                int pp = ppb[mi] + tadd;
                int P = pp >> 1, r = pp & 1;
                int offs = (P << 6) + (slotf(P, g, r) << 3);
                f16x8 ah = *(const f16x8*)&patch[offs];
                f16x8 al = *(const f16x8*)&patch[PLSZ + offs];
                acc0[mi][0] = __builtin_amdgcn_mfma_f32_16x16x32_f16(ah, Bh0, acc0[mi][0], 0, 0, 0);
                acc0[mi][1] = __builtin_amdgcn_mfma_f32_16x16x32_f16(ah, Bh1, acc0[mi][1], 0, 0, 0);
                acc1[mi][0] = __builtin_amdgcn_mfma_f32_16x16x32_f16(ah, Bl0, acc1[mi][0], 0, 0, 0);
                acc1[mi][0] = __builtin_amdgcn_mfma_f32_16x16x32_f16(al, Bh0, acc1[mi][0], 0, 0, 0);
                acc1[mi][1] = __builtin_amdgcn_mfma_f32_16x16x32_f16(ah, Bl1, acc1[mi][1], 0, 0, 0);
                acc1[mi][1] = __builtin_amdgcn_mfma_f32_16x16x32_f16(al, Bh1, acc1[mi][1], 0, 0, 0);
            }
            pB = (tap == 24) ? (pB - 24 * tstride) : (pB + tstride);
            if (tap == 24) { tap = 0; dx = 0; tadd = 0; }
            else {
                tap++; dx++; tadd++;
                if (dx == 5) { dx = 0; tadd += PATCH - 5; }
            }
        }
    }
    #pragma unroll
    for (int mi = 0; mi < 4; ++mi)
        #pragma unroll
        for (int ni = 0; ni < 2; ++ni) {
            int oc = (fg + ni) * 16 + (l & 15);
            float bv = bias[oc];
            #pragma unroll
            for (int reg = 0; reg < 4; ++reg) {
                float v = acc0[mi][ni][reg] + acc1[mi][ni][reg] * (1.f / 4096.f) + bv;
                int pix = mi * 16 + g * 4 + reg;
                int oy = (tyi << 3) + (pix >> 3), ox = (txi << 3) + (pix & 7);
                int idx = ((n * 32 + oy) * 32 + ox) * 256 + oc;
                f16 hh = (f16)v;
                Oh[idx] = __builtin_bit_cast(u16, hh);
                Ol[idx] = f2h((v - (float)hh) * 4096.f);
            }
        }
}

// ============================ quantize v4: A-in-registers, B via LDS double-buffer ============================
__launch_bounds__(256, 2)
__global__ void quant_k(const u16* __restrict__ zh, const u16* __restrict__ zl,
                        const u16* __restrict__ cbf, const float* __restrict__ cbn,
                        const float* __restrict__ cb, u16* __restrict__ e,
                        float* __restrict__ diff) {
    __shared__ u16 Bbuf[2 * 32 * 512];     // [buf][ks*4+pl*2+nf][lane*8]
    __shared__ float cbn_l[1024];
    __shared__ float zn_l[128];
    __shared__ float bd_l[128];
    __shared__ int   wi_l[128];

    int t = threadIdx.x, l = t & 63, wv = t >> 6, g = l >> 4;
    int bi = blockIdx.x;
    int row0 = bi << 7;

    {
        f32x4 v = *(const f32x4*)&cbn[t * 4];
        *(f32x4*)&cbn_l[t * 4] = v;
    }

    f16x8 Ah[2][8], Al[2][8];
    int rbase = row0 + wv * 32 + (l & 15);
    #pragma unroll
    for (int mi = 0; mi < 2; ++mi)
        #pragma unroll
        for (int ks = 0; ks < 8; ++ks) {
            size_t off = (size_t)(rbase + mi * 16) * 256 + ks * 32 + g * 8;
            Ah[mi][ks] = *(const f16x8*)&zh[off];
            Al[mi][ks] = *(const f16x8*)&zl[off];
        }

    #pragma unroll
    for (int mi = 0; mi < 2; ++mi) {
        float s = 0.f;
        #pragma unroll
        for (int ks = 0; ks < 8; ++ks)
            #pragma unroll
            for (int j = 0; j < 8; ++j) {
                float v = (float)Ah[mi][ks][j] + (float)Al[mi][ks][j] * (1.f / 4096.f);
                s = fmaf(v, v, s);
            }
        s += __shfl_xor(s, 16);
        s += __shfl_xor(s, 32);
        if (g == 0) zn_l[wv * 32 + mi * 16 + (l & 15)] = s;
    }

    float rd[8]; int rc[8];
    #pragma unroll
    for (int s = 0; s < 8; ++s) { rd[s] = 1e30f; rc[s] = 0; }

    int fi = wv * 8;
    {
        int no0 = bi & 31;
        #pragma unroll
        for (int q = 0; q < 8; ++q) {
            int f2 = fi + q;
            int ks = f2 >> 2, pl = (f2 >> 1) & 1, nf = f2 & 1;
            f16x8 v = *(const f16x8*)&cbf[(size_t)(((ks * 2 + pl) * 64) + no0 * 2 + nf) * 512 + l * 8];
            *(uint4*)&Bbuf[(size_t)f2 * 512 + l * 8] = __builtin_bit_cast(uint4, v);
        }
    }
    __syncthreads();

    for (int noi = 0; noi < 32; ++noi) {
        int b = noi & 1;
        int no_cur = (noi + bi) & 31;

        f16x8 pf[8];
        if (noi < 31) {
            int no_n = (noi + 1 + bi) & 31;
            #pragma unroll
            for (int q = 0; q < 8; ++q) {
                int f2 = fi + q;
                int ks = f2 >> 2, pl = (f2 >> 1) & 1, nf = f2 & 1;
                pf[q] = *(const f16x8*)&cbf[(size_t)(((ks * 2 + pl) * 64) + no_n * 2 + nf) * 512 + l * 8];
            }
        }

        f32x4 acc0[2][2], acc1[2][2];
        f32x4 z4 = {0.f, 0.f, 0.f, 0.f};
        #pragma unroll
        for (int mi = 0; mi < 2; ++mi)
            #pragma unroll
            for (int nf = 0; nf < 2; ++nf) { acc0[mi][nf] = z4; acc1[mi][nf] = z4; }

        #pragma unroll
        for (int ks = 0; ks < 8; ++ks) {
            const u16* bb = &Bbuf[(size_t)(b * 32 + ks * 4) * 512 + l * 8];
            f16x8 Bh0 = *(const f16x8*)&bb[0 * 512];
            f16x8 Bh1 = *(const f16x8*)&bb[1 * 512];
            f16x8 Bl0 = *(const f16x8*)&bb[2 * 512];
            f16x8 Bl1 = *(const f16x8*)&bb[3 * 512];
            #pragma unroll
            for (int mi = 0; mi < 2; ++mi) {
                acc0[mi][0] = __builtin_amdgcn_mfma_f32_16x16x32_f16(Ah[mi][ks], Bh0, acc0[mi][0], 0, 0, 0);
                acc0[mi][1] = __builtin_amdgcn_mfma_f32_16x16x32_f16(Ah[mi][ks], Bh1, acc0[mi][1], 0, 0, 0);
                acc1[mi][0] = __builtin_amdgcn_mfma_f32_16x16x32_f16(Ah[mi][ks], Bl0, acc1[mi][0], 0, 0, 0);
                acc1[mi][0] = __builtin_amdgcn_mfma_f32_16x16x32_f16(Al[mi][ks], Bh0, acc1[mi][0], 0, 0, 0);
                acc1[mi][1] = __builtin_amdgcn_mfma_f32_16x16x32_f16(Ah[mi][ks], Bl1, acc1[mi][1], 0, 0, 0);
                acc1[mi][1] = __builtin_amdgcn_mfma_f32_16x16x32_f16(Al[mi][ks], Bh1, acc1[mi][1], 0, 0, 0);
            }
        }

        #pragma unroll
        for (int nf = 0; nf < 2; ++nf) {
            int col = no_cur * 32 + nf * 16 + (l & 15);
            float cn = cbn_l[col];
            #pragma unroll
            for (int mi = 0; mi < 2; ++mi)
                #pragma unroll
                for (int reg = 0; reg < 4; ++reg) {
                    float d = cn - 2.f * (acc0[mi][nf][reg] + acc1[mi][nf][reg] * (1.f / 4096.f));
                    int slot = mi * 4 + reg;
                    if (d < rd[slot] || (d == rd[slot] && col < rc[slot])) { rd[slot] = d; rc[slot] = col; }
                }
        }

        if (noi < 31) {
            #pragma unroll
            for (int q = 0; q < 8; ++q)
                *(uint4*)&Bbuf[(size_t)((1 - b) * 32 + fi + q) * 512 + l * 8] = __builtin_bit_cast(uint4, pf[q]);
        }
        __syncthreads();
    }

    #pragma unroll
    for (int step = 1; step < 16; step <<= 1) {
        #pragma unroll
        for (int s = 0; s < 8; ++s) {
            float od = __shfl_xor(rd[s], step);
            int ocl = __shfl_xor(rc[s], step);
            if (od < rd[s] || (od == rd[s] && ocl < rc[s])) { rd[s] = od; rc[s] = ocl; }
        }
    }
    if ((l & 15) == 0) {
        #pragma unroll
        for (int s = 0; s < 8; ++s) {
            int mi = s >> 2, reg = s & 3;
            int row = wv * 32 + mi * 16 + g * 4 + reg;
            bd_l[row] = rd[s]; wi_l[row] = rc[s];
        }
    }
    __syncthreads();
    if (t < 64) {
        float dval = (zn_l[t] + bd_l[t]) + (zn_l[t + 64] + bd_l[t + 64]);
        #pragma unroll
        for (int step = 1; step < 64; step <<= 1) dval += __shfl_xor(dval, step);
        if (t == 0) atomicAdd(diff, dval * (1.f / 16777216.f));
    }
    __syncthreads();
    // e-write: 4 independent load->store chains in flight (was 1 serial chain)
    for (int r = 0; r < 128; r += 4) {
        int wiA = wi_l[r], wiB = wi_l[r + 1], wiC = wi_l[r + 2], wiD = wi_l[r + 3];
        float vA = cb[wiA * 256 + t];
        float vB = cb[wiB * 256 + t];
        float vC = cb[wiC * 256 + t];
        float vD = cb[wiD * 256 + t];
        e[(size_t)(row0 + r) * 256 + t]     = f2h(vA);
        e[(size_t)(row0 + r + 1) * 256 + t] = f2h(vB);
        e[(size_t)(row0 + r + 2) * 256 + t] = f2h(vC);
        e[(size_t)(row0 + r + 3) * 256 + t] = f2h(vD);
    }
}

// ============================ deconv k4 s2 p1, ALL 4 PARITIES per block ============================
template<int ICT>
__launch_bounds__(256)
__global__ void deconv4m_k(const u16* __restrict__ in, const u16* __restrict__ wdf,
                           const float* __restrict__ bias, u16* __restrict__ out,
                           int IH, int IW) {
    constexpr int ICC = ICT / 32;
    constexpr int RST = ICT + 8;              // halves per pixel line
    constexpr int CHK = ICT / 8;              // uint4 chunks per pixel
    __shared__ u16 patch[100 * RST];

    int t = threadIdx.x, l = t & 63, wv = t >> 6;
    int wm = wv >> 1, wn = wv & 1, g = l >> 4;

    int bi = blockIdx.x;
    int wlin = (bi & 7) * ((int)gridDim.x >> 3) + (bi >> 3);
    int tw = IW >> 3, th = IH >> 3;
    int txi = wlin % tw; int rest = wlin / tw;
    int tyi = rest % th; int n = rest / th;
    int a0 = tyi << 3, b0 = txi << 3;
    int OH = IH << 1, OW = IW << 1;

    // stage 10x10 window rows a0-1..a0+8, cols b0-1..b0+8, all ICT channels
    for (int i = t; i < 100 * CHK; i += 256) {
        int c = i % CHK; int pp = i / CHK;
        int pr = pp / 10, pc = pp - pr * 10;
        int ar = a0 - 1 + pr, ac = b0 - 1 + pc;
        uint4 v = make_uint4(0u, 0u, 0u, 0u);
        if ((unsigned)ar < (unsigned)IH && (unsigned)ac < (unsigned)IW)
            v = *(const uint4*)&in[((size_t)(n * IH + ar) * IW + ac) * ICT + c * 8];
        *(uint4*)&patch[(pr * 10 + pc) * RST + c * 8] = v;
    }
    __syncthreads();

    int pb0[2];
    #pragma unroll
    for (int mi = 0; mi < 2; ++mi) {
        int m = wm * 32 + mi * 16 + (l & 15);
        pb0[mi] = ((m >> 3) * 10 + (m & 7)) * RST + g * 8;
    }

    float bv[2];
    #pragma unroll
    for (int ni = 0; ni < 2; ++ni) bv[ni] = bias[wn * 32 + ni * 16 + (l & 15)];

    auto ldB = [&](int par, int icc, int tt, f16x8* B) {
        int ry = par >> 1, rx = par & 1;
        int tty = tt >> 1, ttx = tt & 1;
        int tap = (1 - ry + 2 * tty) * 4 + (1 - rx + 2 * ttx);
        #pragma unroll
        for (int ni = 0; ni < 2; ++ni)
            B[ni] = *(const f16x8*)&wdf[(size_t)((tap * ICC + icc) * 4 + wn * 2 + ni) * 512 + l * 8];
    };

    constexpr int NSTEP = 4 * ICC * 4;
    constexpr int ICSH = (ICC == 2) ? 1 : 3;

    f16x8 B0[2], B1[2];
    ldB(0, 0, 0, B0);

    for (int par = 0; par < 4; ++par) {
        int ry = par >> 1, rx = par & 1;
        f32x4 acc[2][2];
        f32x4 z4 = {0.f, 0.f, 0.f, 0.f};
        #pragma unroll
        for (int mi = 0; mi < 2; ++mi)
            #pragma unroll
            for (int ni = 0; ni < 2; ++ni) acc[mi][ni] = z4;

        for (int icc = 0; icc < ICC; ++icc) {
            #pragma unroll
            for (int tt = 0; tt < 4; ++tt) {
                int s1 = ((par * ICC + icc) << 2) + tt + 1;
                if (s1 < NSTEP) {
                    int tn = s1 & 3;
                    int in_ = (s1 >> 2) & (ICC - 1);
                    int pn = s1 >> (2 + ICSH);
                    ldB(pn, in_, tn, B1);
                }
                int tty = tt >> 1, ttx = tt & 1;
                int shift = ((1 - tty + ry) * 10 + (1 - ttx + rx)) * RST + icc * 32;
                #pragma unroll
                for (int mi = 0; mi < 2; ++mi) {
                    f16x8 a = *(const f16x8*)&patch[pb0[mi] + shift];
                    #pragma unroll
                    for (int ni = 0; ni < 2; ++ni)
                        acc[mi][ni] = __builtin_amdgcn_mfma_f32_16x16x32_f16(a, B0[ni], acc[mi][ni], 0, 0, 0);
                }
                B0[0] = B1[0]; B0[1] = B1[1];
            }
        }
        #pragma unroll
        for (int mi = 0; mi < 2; ++mi)
            #pragma unroll
            for (int ni = 0; ni < 2; ++ni) {
                int oc = wn * 32 + ni * 16 + (l & 15);
                #pragma unroll
                for (int reg = 0; reg < 4; ++reg) {
                    float v = fmaxf(acc[mi][ni][reg] + bv[ni], 0.f);
                    int pix = wm * 32 + mi * 16 + g * 4 + reg;
                    int oy = ((a0 + (pix >> 3)) << 1) + ry;
                    int ox = ((b0 + (pix & 7)) << 1) + rx;
                    out[((size_t)(n * OH + oy) * OW + ox) * 64 + oc] = f2h(v);
                }
            }
    }
}

// ============================ final conv 3x3 64->1, p1, tanh (LDS-tiled, v_dot2) ============================
__launch_bounds__(256)
__global__ void conv3x3_tanh_k(const u16* __restrict__ in, const float* __restrict__ w,
                               const float* __restrict__ b, float* __restrict__ out) {
    __shared__ u16 tile[18 * 18 * 72];
    __shared__ u32 wpk[288];   // [tap][icp] half2-packed weights
    int t = threadIdx.x;
    int bi = blockIdx.x;
    int wlin = (bi & 7) * ((int)gridDim.x >> 3) + (bi >> 3);
    int n = wlin >> 6;
    int tile6 = wlin & 63;
    int ty0 = (tile6 >> 3) << 4, tx0 = (tile6 & 7) << 4;

    for (int i = t; i < 288; i += 256) {
        int tap = i >> 5, icp = i & 31;
        h2 p;
        p.x = (f16)w[(2 * icp) * 9 + tap];
        p.y = (f16)w[(2 * icp + 1) * 9 + tap];
        wpk[tap * 32 + icp] = __builtin_bit_cast(u32, p);
    }
    for (int i = t; i < 2592; i += 256) {
        int ch = i & 7, pix = i >> 3;
        int pr = pix / 18, pc = pix - pr * 18;
        int gy = ty0 - 1 + pr, gx = tx0 - 1 + pc;
        uint4 v = make_uint4(0u, 0u, 0u, 0u);
        if ((unsigned)gy < 128u && (unsigned)gx < 128u)
            v = *(const uint4*)&in[(((n << 7) + gy) * 128 + gx) * 64 + ch * 8];
        *(uint4*)&tile[pix * 72 + ch * 8] = v;
    }
    __syncthreads();

    int ty = t >> 4, tx = t & 15;
    float acc = b[0];
    #pragma unroll
    for (int dy = 0; dy < 3; ++dy) {
        #pragma unroll
        for (int dx = 0; dx < 3; ++dx) {
            int base = ((ty + dy) * 18 + (tx + dx)) * 72;
            const u32* wp = &wpk[(dy * 3 + dx) * 32];
            #pragma unroll
            for (int c8 = 0; c8 < 8; ++c8) {
                uint4 v = *(const uint4*)&tile[base + c8 * 8];
                acc = __builtin_amdgcn_fdot2(__builtin_bit_cast(h2, v.x),
                        __builtin_bit_cast(h2, wp[c8 * 4 + 0]), acc, false);
                acc = __builtin_amdgcn_fdot2(__builtin_bit_cast(h2, v.y),
                        __builtin_bit_cast(h2, wp[c8 * 4 + 1]), acc, false);
                acc = __builtin_amdgcn_fdot2(__builtin_bit_cast(h2, v.z),
                        __builtin_bit_cast(h2, wp[c8 * 4 + 2]), acc, false);
                acc = __builtin_amdgcn_fdot2(__builtin_bit_cast(h2, v.w),
                        __builtin_bit_cast(h2, wp[c8 * 4 + 3]), acc, false);
            }
        }
    }
    int oy = ty0 + ty, ox = tx0 + tx;
    out[(n << 14) + (oy << 7) + ox] = tanhf(acc);
}

extern "C" void kernel_launch(void* const* d_in, const int* in_sizes, int n_in,
                              void* d_out, int out_size, void* d_ws, size_t ws_size,
                              hipStream_t stream) {
    (void)in_sizes; (void)n_in; (void)out_size; (void)ws_size;
    const float* x   = (const float*)d_in[0];
    const float* ew1 = (const float*)d_in[1];
    const float* eb1 = (const float*)d_in[2];
    const float* ew2 = (const float*)d_in[3];
    const float* eb2 = (const float*)d_in[4];
    const float* ew3 = (const float*)d_in[5];
    const float* eb3 = (const float*)d_in[6];
    const float* cb  = (const float*)d_in[7];
    const float* dw1 = (const float*)d_in[8];
    const float* db1 = (const float*)d_in[9];
    const float* dw2 = (const float*)d_in[10];
    const float* db2 = (const float*)d_in[11];
    const float* dw3 = (const float*)d_in[12];
    const float* db3 = (const float*)d_in[13];
    float* out = (float*)d_out;

    u16* ws = (u16*)d_ws;
    u16* a1h = ws;             u16* a1l = ws + 16777216;
    u16* zh  = ws;             u16* zl  = ws + 16777216;
    u16* a2h = ws + 33554432;  u16* a2l = ws + 50331648;
    u16* e   = ws + 33554432;
    u16* y1  = ws + 67108864;
    u16* y2  = ws;
    u16* wBf2 = ws + 83886080;          // 204800
    u16* wBf3 = wBf2 + 204800;          // 819200
    u16* wd1f = wBf3 + 819200;          // 262144
    u16* wd2f = wd1f + 262144;          // 65536
    u16* cbf  = wd2f + 65536;           // 524288
    float* cbn = (float*)(cbf + 524288);

    prep_all_k<<<7333, 256, 0, stream>>>(ew2, ew3, dw1, dw2, cb,
                                         wBf2, wBf3, wd1f, wd2f, cbf, cbn,
                                         out + 1048576);

    conv1_k<<<1024, 256, 0, stream>>>(x, ew1, eb1, a1h, a1l);
    conv5w_k<<<1024, 256, 0, stream>>>(a1h, a1l, wBf2, eb2, a2h, a2l);
    conv5x_k<<<1024, 512, 0, stream>>>(a2h, a2l, wBf3, eb3, zh, zl);
    quant_k<<<512, 256, 0, stream>>>(zh, zl, cbf, cbn, cb, e, out + 1048576);
    deconv4m_k<256><<<1024, 256, 0, stream>>>(e, wd1f, db1, y1, 32, 32);
    deconv4m_k<64><<<4096, 256, 0, stream>>>(y1, wd2f, db2, y2, 64, 64);
    conv3x3_tanh_k<<<4096, 256, 0, stream>>>(y2, dw3, db3, out);
}